// Round 7
// baseline (698.635 us; speedup 1.0000x reference)
//
#include <hip/hip_runtime.h>

typedef unsigned short u16;
typedef short short8 __attribute__((ext_vector_type(8)));
typedef unsigned short ushort8 __attribute__((ext_vector_type(8)));
typedef unsigned short bf16x4 __attribute__((ext_vector_type(4)));
typedef float f32x4 __attribute__((ext_vector_type(4)));

#define DEVINL __device__ __forceinline__

DEVINL float bf2f(u16 u) {
  unsigned int x = ((unsigned int)u) << 16;
  return __builtin_bit_cast(float, x);
}
DEVINL u16 f2bf(float f) {
  unsigned int x = __builtin_bit_cast(unsigned int, f);
  x += 0x7FFFu + ((x >> 16) & 1u);  // RNE
  return (u16)(x >> 16);
}

// Problem constants: B=2, S=2048, E=1024, H=16, DH=64
// Inputs float32; big operands converted once to bf16; MFMA internally;
// final output written as float32.

// ---------------------------------------------------------------------------
// Fused f32 -> bf16 conversion of query + 4 weight matrices.
// ---------------------------------------------------------------------------
__global__ __launch_bounds__(256) void cvt_all(
    const float* __restrict__ q, const float* __restrict__ wq,
    const float* __restrict__ wk, const float* __restrict__ wv,
    const float* __restrict__ wo, u16* __restrict__ out) {
  int i = blockIdx.x * 256 + threadIdx.x;  // < 1048576
  const float* src;
  size_t off8;
  if (i < 524288) { src = q;  off8 = i; }
  else if (i < 655360) { src = wq; off8 = i - 524288; }
  else if (i < 786432) { src = wk; off8 = i - 655360; }
  else if (i < 917504) { src = wv; off8 = i - 786432; }
  else { src = wo; off8 = i - 917504; }
  f32x4 a = ((const f32x4*)src)[2 * off8];
  f32x4 b = ((const f32x4*)src)[2 * off8 + 1];
  ushort8 o;
#pragma unroll
  for (int e = 0; e < 4; ++e) o[e] = f2bf(a[e]);
#pragma unroll
  for (int e = 0; e < 4; ++e) o[4 + e] = f2bf(b[e]);
  ((ushort8*)out)[i] = o;
}

// ---------------------------------------------------------------------------
// NT GEMM (bf16 in via MFMA): C[i,j] = scale * sum_k A[i,k]*B[j,k] (+ bias[j])
// ---------------------------------------------------------------------------
template <int BM, int BN, bool TRANSV, bool HASBIAS, bool OUTF32>
__global__ __launch_bounds__(256) void gemm_nt(
    const u16* __restrict__ A, const u16* __restrict__ Bm,
    const float* __restrict__ bias, void* __restrict__ C,
    int K, int lda, int ldb, int ldc, float scale,
    long long sAh, long long sBh, long long sCh) {
  constexpr int LDSS = 40;  // padded LDS row stride (u16)
  constexpr int WM = BM / 2, WN = BN / 2, FM = WM / 16, FN = WN / 16;
  constexpr int AIN = BM / 64;
  constexpr int BIN = BN / 64;

  __shared__ alignas(16) u16 As[BM * LDSS];
  __shared__ alignas(16) u16 Bs[BN * LDSS];

  const int tid = threadIdx.x;
  const int lane = tid & 63;
  const int wv = tid >> 6;
  const int wy = wv >> 1, wx = wv & 1;
  const int quad = lane >> 4, mrow = lane & 15;

  const int z = blockIdx.z;
  const u16* Ap = A + z * sAh;
  const u16* Bp = Bm + z * sBh;
  u16* Cp = (u16*)C + z * sCh;
  float* Cf = (float*)C + z * sCh;

  const int row0 = blockIdx.y * BM;
  const int col0 = blockIdx.x * BN;

  f32x4 acc[FM][FN];
#pragma unroll
  for (int i = 0; i < FM; ++i)
#pragma unroll
    for (int j = 0; j < FN; ++j) acc[i][j] = f32x4{0.f, 0.f, 0.f, 0.f};

  for (int k0 = 0; k0 < K; k0 += 32) {
    ushort8 ta[AIN], tb[BIN];
#pragma unroll
    for (int r = 0; r < AIN; ++r) {
      int idx = r * 256 + tid;
      int row = idx >> 2, ch = idx & 3;
      ta[r] = *(const ushort8*)(Ap + (size_t)(row0 + row) * lda + k0 + ch * 8);
    }
#pragma unroll
    for (int r = 0; r < BIN; ++r) {
      int idx = r * 256 + tid;
      int row = idx >> 2, ch = idx & 3;
      tb[r] = *(const ushort8*)(Bp + (size_t)(col0 + row) * ldb + k0 + ch * 8);
    }
    __syncthreads();  // previous iteration's LDS reads done
#pragma unroll
    for (int r = 0; r < AIN; ++r) {
      int idx = r * 256 + tid;
      int row = idx >> 2, ch = idx & 3;
      *(ushort8*)&As[row * LDSS + ch * 8] = ta[r];
    }
#pragma unroll
    for (int r = 0; r < BIN; ++r) {
      int idx = r * 256 + tid;
      int row = idx >> 2, ch = idx & 3;
      *(ushort8*)&Bs[row * LDSS + ch * 8] = tb[r];
    }
    __syncthreads();

    short8 af[FM], bfr[FN];
#pragma unroll
    for (int mi = 0; mi < FM; ++mi)
      af[mi] = *(const short8*)&As[(wy * WM + mi * 16 + mrow) * LDSS + quad * 8];
#pragma unroll
    for (int ni = 0; ni < FN; ++ni)
      bfr[ni] = *(const short8*)&Bs[(wx * WN + ni * 16 + mrow) * LDSS + quad * 8];
#pragma unroll
    for (int mi = 0; mi < FM; ++mi)
#pragma unroll
      for (int ni = 0; ni < FN; ++ni)
        acc[mi][ni] = __builtin_amdgcn_mfma_f32_16x16x32_bf16(
            af[mi], bfr[ni], acc[mi][ni], 0, 0, 0);
  }

  // Epilogue. C/D layout: col = lane&15, row = quad*4 + r  [m89/m91 verified]
#pragma unroll
  for (int mi = 0; mi < FM; ++mi) {
    const int rowb = row0 + wy * WM + mi * 16 + quad * 4;
#pragma unroll
    for (int ni = 0; ni < FN; ++ni) {
      const int col = col0 + wx * WN + ni * 16 + mrow;
      float bv = 0.f;
      if (HASBIAS) bv = bias[col];
      f32x4 v = acc[mi][ni];
      if (OUTF32) {
#pragma unroll
        for (int r = 0; r < 4; ++r)
          Cf[(size_t)(rowb + r) * ldc + col] = v[r] * scale + bv;
      } else if (!TRANSV) {
#pragma unroll
        for (int r = 0; r < 4; ++r)
          Cp[(size_t)(rowb + r) * ldc + col] = f2bf(v[r] * scale + bv);
      } else {
        // Ct[b][col][s], per-batch stride E*S = 2097152
        const int bb = rowb >> 11;
        const int ss = rowb & 2047;
        bf16x4 pk;
#pragma unroll
        for (int r = 0; r < 4; ++r) pk[r] = f2bf(v[r] * scale + bv);
        *(bf16x4*)(Cp + (size_t)bb * 2097152 + (size_t)col * 2048 + ss) = pk;
      }
    }
  }
}

// ---------------------------------------------------------------------------
// Fused conv(KS=3, cross-head) + online softmax + PV, flash-style.
// Per batch: SC = raw scores [h][q 2048][k 2048] bf16, Vt = [e 1024][k 2048],
// At out = [q 2048][e 1024] bf16. Grid 256 blocks; block = 512 thr = 8 waves,
// q-tile = 8 (q0 = blockIdx.x*8). k iterated in 32 chunks of 64.
// Roles per wave w: conv for q=w; PV/O-accum for heads {2w, 2w+1}.
// conv MFMA (round-6 verified): m=h, n=k, kdim=(i,d); A-frags from conv_w.
// P chunk goes through LDS Pl[h][q][k] (A-layout for PV). V B-frags read
// directly from global Vt (L2/L3-resident, 16 full cache lines per instr).
// conv_b skipped: constant along softmax (k) axis -> cancels exactly.
// ---------------------------------------------------------------------------
__global__ __launch_bounds__(512) void conv_attn(
    const u16* __restrict__ SC, const u16* __restrict__ Vt,
    const float* __restrict__ cw, u16* __restrict__ At) {
  constexpr int TROW = 24;                  // T h-stride (48B, 16B-aligned)
  constexpr int TSLAB = 66 * TROW;          // per-q slab (u16)
  constexpr int PROW = 72;                  // Pl k-stride (144B, 16B-aligned)
  __shared__ alignas(16) u16 T[8 * TSLAB];     // [q][kk 0..65][h] 25.3 KB
  __shared__ alignas(16) u16 Pl[16 * 8 * PROW];// [h][q][k]       18.4 KB
  __shared__ float alphaS[16][16];
  __shared__ float lS[16][16];

  const int tid = threadIdx.x;
  const int lane = tid & 63;
  const int wv = tid >> 6;       // 0..7
  const int n = lane & 15;
  const int quad = lane >> 4;
  const int q0 = blockIdx.x * 8;

  if (tid < 256) {  // init (only q>=8 rows matter; q<8 overwritten per chunk)
    alphaS[tid >> 4][tid & 15] = 1.f;
    lS[tid >> 4][tid & 15] = 1.f;
  }

  // conv A-frags (round-6 verified): lane's M-row h = n; kdim=quad*8+j -> (i,d)
  short8 a1, a2;
#pragma unroll
  for (int j = 0; j < 8; ++j) {
    const int kd = quad * 8 + j;
    const int i = kd & 15, d = kd >> 4;
    a1[j] = (short)f2bf(cw[n * 48 + i * 3 + d]);
    a2[j] = (quad < 2) ? (short)f2bf(cw[n * 48 + kd * 3 + 2]) : (short)0;
  }

  float m[4], l[4];
#pragma unroll
  for (int r = 0; r < 4; ++r) { m[r] = -3e38f; l[r] = 0.f; }
  f32x4 O[2][4];
#pragma unroll
  for (int hh = 0; hh < 2; ++hh)
#pragma unroll
    for (int dt = 0; dt < 4; ++dt) O[hh][dt] = f32x4{0.f, 0.f, 0.f, 0.f};

#pragma unroll 1
  for (int c = 0; c < 32; ++c) {
    const int k0 = c * 64;
    // ---- stage S-chunk transposed: T[q][kk][h], kk = k - k0 + 1 ----
#pragma unroll
    for (int rr = 0; rr < 2; ++rr) {
      const int idx = rr * 512 + tid;        // < 1024
      const int k8 = idx & 7;                // 8 groups of 8 k
      const int pair = idx >> 3;             // q*16 + h
      const int qq = pair >> 4, h = pair & 15;
      ushort8 v = *(const ushort8*)(SC + ((size_t)(h * 2048 + q0 + qq) * 2048) + k0 + k8 * 8);
#pragma unroll
      for (int e0 = 0; e0 < 8; ++e0) {
        const int e = (e0 + k8) & 7;  // rotate to spread banks
        T[qq * TSLAB + (1 + k8 * 8 + e) * TROW + h] = v[e];
      }
    }
    if (tid < 256) {  // halo rows kk=0 (k0-1) and kk=65 (k0+64)
      const int top = tid >> 7, p2 = tid & 127;
      const int qq = p2 >> 4, h = p2 & 15;
      const int k = k0 + (top ? 64 : -1);
      u16 val = 0;
      if ((unsigned)k < 2048u) val = SC[(size_t)(h * 2048 + q0 + qq) * 2048 + k];
      T[qq * TSLAB + (top ? 65 : 0) * TROW + h] = val;
    }

    // ---- PV of previous chunk (overlaps staging latency) ----
    if (c > 0) {
      const int k0p = k0 - 64;
#pragma unroll
      for (int hh = 0; hh < 2; ++hh) {
        const int h = wv * 2 + hh;
        float av[4];
#pragma unroll
        for (int r = 0; r < 4; ++r) av[r] = alphaS[h][quad * 4 + r];
#pragma unroll
        for (int dt = 0; dt < 4; ++dt)
#pragma unroll
          for (int r = 0; r < 4; ++r) O[hh][dt][r] *= av[r];
#pragma unroll
        for (int ks = 0; ks < 2; ++ks) {
          const short8 aF = *(const short8*)&Pl[(h * 8 + (n & 7)) * PROW + ks * 32 + quad * 8];
#pragma unroll
          for (int dt = 0; dt < 4; ++dt) {
            const short8 bF = *(const short8*)(Vt + (size_t)(h * 64 + dt * 16 + n) * 2048 + k0p + ks * 32 + quad * 8);
            O[hh][dt] = __builtin_amdgcn_mfma_f32_16x16x32_bf16(aF, bF, O[hh][dt], 0, 0, 0);
          }
        }
      }
    }
    __syncthreads();  // T ready; Pl/alphaS consumed

    // ---- conv + online softmax for q = wv ----
    {
      const int qq = wv;
      f32x4 x[4];
#pragma unroll
      for (int kt = 0; kt < 4; ++kt) {
        const short8 b1 = *(const short8*)&T[qq * TSLAB + (kt * 16 + n + (quad >> 1)) * TROW + (quad & 1) * 8];
        const short8 b2 = *(const short8*)&T[qq * TSLAB + (kt * 16 + n + 2) * TROW + (quad & 1) * 8];
        f32x4 acc = f32x4{0.f, 0.f, 0.f, 0.f};
        acc = __builtin_amdgcn_mfma_f32_16x16x32_bf16(a1, b1, acc, 0, 0, 0);
        acc = __builtin_amdgcn_mfma_f32_16x16x32_bf16(a2, b2, acc, 0, 0, 0);
        x[kt] = acc;
      }
      float mn[4], al[4], s[4];
#pragma unroll
      for (int r = 0; r < 4; ++r) {
        float cm = fmaxf(fmaxf(x[0][r], x[1][r]), fmaxf(x[2][r], x[3][r]));
#pragma unroll
        for (int off = 1; off < 16; off <<= 1) cm = fmaxf(cm, __shfl_xor(cm, off));
        mn[r] = fmaxf(m[r], cm);
        al[r] = __expf(m[r] - mn[r]);
        s[r] = 0.f;
      }
#pragma unroll
      for (int kt = 0; kt < 4; ++kt)
#pragma unroll
        for (int r = 0; r < 4; ++r) {
          x[kt][r] = __expf(x[kt][r] - mn[r]);
          s[r] += x[kt][r];
        }
#pragma unroll
      for (int r = 0; r < 4; ++r) {
#pragma unroll
        for (int off = 1; off < 16; off <<= 1) s[r] += __shfl_xor(s[r], off);
        l[r] = l[r] * al[r] + s[r];
        m[r] = mn[r];
      }
      // write P chunk (A-layout source) + alpha
#pragma unroll
      for (int kt = 0; kt < 4; ++kt)
#pragma unroll
        for (int r = 0; r < 4; ++r)
          Pl[((quad * 4 + r) * 8 + qq) * PROW + kt * 16 + n] = f2bf(x[kt][r]);
      if (n == 0)
#pragma unroll
        for (int r = 0; r < 4; ++r) alphaS[quad * 4 + r][qq] = al[r];
    }
    __syncthreads();  // Pl/alphaS ready for PV next iter
  }

  // ---- final PV (chunk 31) ----
  {
    const int k0p = 31 * 64;
#pragma unroll
    for (int hh = 0; hh < 2; ++hh) {
      const int h = wv * 2 + hh;
      float av[4];
#pragma unroll
      for (int r = 0; r < 4; ++r) av[r] = alphaS[h][quad * 4 + r];
#pragma unroll
      for (int dt = 0; dt < 4; ++dt)
#pragma unroll
        for (int r = 0; r < 4; ++r) O[hh][dt][r] *= av[r];
#pragma unroll
      for (int ks = 0; ks < 2; ++ks) {
        const short8 aF = *(const short8*)&Pl[(h * 8 + (n & 7)) * PROW + ks * 32 + quad * 8];
#pragma unroll
        for (int dt = 0; dt < 4; ++dt) {
          const short8 bF = *(const short8*)(Vt + (size_t)(h * 64 + dt * 16 + n) * 2048 + k0p + ks * 32 + quad * 8);
          O[hh][dt] = __builtin_amdgcn_mfma_f32_16x16x32_bf16(aF, bF, O[hh][dt], 0, 0, 0);
        }
      }
    }
  }
  // publish l, then normalize + store (rows q = quad*4+r < 8 only)
  if (n == 0)
#pragma unroll
    for (int r = 0; r < 4; ++r) lS[quad * 4 + r][wv] = l[r];
  __syncthreads();
#pragma unroll
  for (int hh = 0; hh < 2; ++hh) {
    const int h = wv * 2 + hh;
    if (quad < 2) {
      float inv[4];
#pragma unroll
      for (int r = 0; r < 4; ++r) inv[r] = 1.f / lS[h][quad * 4 + r];
#pragma unroll
      for (int dt = 0; dt < 4; ++dt)
#pragma unroll
        for (int r = 0; r < 4; ++r)
          At[(size_t)(q0 + quad * 4 + r) * 1024 + h * 64 + dt * 16 + n] =
              f2bf(O[hh][dt][r] * inv[r]);
    }
  }
}

// Diagnostic: fill f32 output with 2000.0 (ws-too-small marker).
__global__ void fill_diag(float* out, int n) {
  int i = blockIdx.x * 256 + threadIdx.x;
  if (i < n) out[i] = 2000.0f;
}

extern "C" void kernel_launch(void* const* d_in, const int* in_sizes, int n_in,
                              void* d_out, int out_size, void* d_ws, size_t ws_size,
                              hipStream_t stream) {
  const float* query = (const float*)d_in[0];
  const float* Wq = (const float*)d_in[1];
  const float* bq = (const float*)d_in[2];
  const float* Wk = (const float*)d_in[3];
  const float* bk = (const float*)d_in[4];
  const float* Wv = (const float*)d_in[5];
  const float* bv = (const float*)d_in[6];
  const float* Wo = (const float*)d_in[7];
  const float* bo = (const float*)d_in[8];
  const float* cw = (const float*)d_in[9];
  // d_in[10] (conv_b) intentionally unused: cancels in softmax.

  const size_t SE = (size_t)4096 * 1024;  // B*S*E elems
  const size_t WE = (size_t)1024 * 1024;  // E*E elems
  const size_t SCE = (size_t)16 * 2048 * 2048;  // per-batch scores elems
  const size_t fixedB = ((SE + 4 * WE) + 4 * SE) * sizeof(u16);  // 48 MiB
  if (ws_size < fixedB + SCE * sizeof(u16)) {  // 48 + 128 MiB
    fill_diag<<<dim3((out_size + 255) / 256), dim3(256), 0, stream>>>(
        (float*)d_out, out_size);
    return;
  }

  u16* ws = (u16*)d_ws;
  u16* Qb = ws;              // bf16 query [b][s][e]
  u16* Wqb = Qb + SE;        // bf16 weights (contiguous after Qb for cvt_all)
  u16* Wkb = Wqb + WE;
  u16* Wvb = Wkb + WE;
  u16* Wob = Wvb + WE;
  u16* Qw = Wob + WE;        // [b][s][e]
  u16* Kw = Qw + SE;         // [b][s][e]
  u16* Vt = Kw + SE;         // [b][e][s] transposed V
  u16* At = Vt + SE;         // attention output [b][s][e] (bf16)
  u16* SC = At + SE;         // raw scores, one batch at a time [h][q][k]

  dim3 blk(256);
  cvt_all<<<dim3(4096), blk, 0, stream>>>(query, Wq, Wk, Wv, Wo, Qb);

  // Q/K/V projections (M=4096, N=1024, K=1024), bf16 out
  gemm_nt<128, 128, false, true, false><<<dim3(8, 32, 1), blk, 0, stream>>>(
      Qb, Wqb, bq, Qw, 1024, 1024, 1024, 1024, 1.f, 0, 0, 0);
  gemm_nt<128, 128, false, true, false><<<dim3(8, 32, 1), blk, 0, stream>>>(
      Qb, Wkb, bk, Kw, 1024, 1024, 1024, 1024, 1.f, 0, 0, 0);
  gemm_nt<128, 128, true, true, false><<<dim3(8, 32, 1), blk, 0, stream>>>(
      Qb, Wvb, bv, Vt, 1024, 1024, 1024, 1024, 1.f, 0, 0, 0);

  for (int b = 0; b < 2; ++b) {
    const size_t bQK = (size_t)b * 2097152;
    // raw scores = Q Kh^T / 8 per head: M=N=2048, K=64, z = head
    gemm_nt<128, 128, false, false, false>
        <<<dim3(16, 16, 16), blk, 0, stream>>>(
            Qw + bQK, Kw + bQK, nullptr, SC,
            64, 1024, 1024, 2048, 0.125f, 64LL, 64LL, 4194304LL);
    // fused conv + online-softmax + PV
    conv_attn<<<dim3(256), dim3(512), 0, stream>>>(
        SC, Vt + bQK, cw, At + bQK);
  }

  // output projection -> f32 d_out
  gemm_nt<128, 128, false, true, true><<<dim3(8, 32, 1), blk, 0, stream>>>(
      At, Wob, bo, d_out, 1024, 1024, 1024, 1024, 1.f, 0, 0, 0);
}